// Round 13
// baseline (159.015 us; speedup 1.0000x reference)
//
#include <hip/hip_runtime.h>
#include <hip/hip_bf16.h>
#include <stdint.h>

#define BATCH 8
#define CH    64
#define HH    256
#define WW    256
#define TW    32
#define TH    16
#define PW    34          // TW+2
#define PH    18          // TH+2
#define NPIX  (PH*PW)     // 612
#define WELEM 36864       // 9*64*64

typedef __attribute__((ext_vector_type(8))) short short8;
typedef __attribute__((ext_vector_type(4))) float float4v;

__device__ __forceinline__ int swz(int byte) {
    // 128B-row XOR swizzle — proven 0-conflict (rounds 0-12) for 16B fragment reads
    return byte ^ (((byte >> 7) & 7) << 4);
}

__device__ __forceinline__ unsigned short f2bf(float v) {
    __hip_bfloat16 h = __float2bfloat16(v);
    return *reinterpret_cast<unsigned short*>(&h);
}

__device__ __forceinline__ float bf2f(unsigned short u) {
    unsigned int x = ((unsigned int)u) << 16;
    return *reinterpret_cast<float*>(&x);
}

// async global->LDS, 16B per lane; zero VGPR cost.
// CONTRACT (m104/m108): LDS dest = readfirstlane(base) + lane*16. Only call with
// full-wave or lane-0-anchored-prefix exec and per-lane-linear lds addresses.
__device__ __forceinline__ void gl16(const void* g, void* l) {
    __builtin_amdgcn_global_load_lds(
        (const __attribute__((address_space(1))) unsigned int*)g,
        (__attribute__((address_space(3))) unsigned int*)l, 16, 0, 0);
}

// ---------------- fused prep: weights + gmax + transpose in ONE launch ----------------
// blocks [0,72):    weight prep  f32 OIHW -> bf16 [kk][o][c] PRE-SWIZZLED
// blocks [72,584):  gmax 3x3 maxpool of gate -> gmax image (scratch in `out`)
// blocks [584,2632): transpose x NCHW f32 -> xbf NHWC bf16 (4 tiles per block)
__global__ __launch_bounds__(1024)
void prep_all(const float* __restrict__ w1, const float* __restrict__ w2,
              const float* __restrict__ x, const float* __restrict__ gate,
              unsigned short* __restrict__ w1p, unsigned short* __restrict__ w2p,
              unsigned short* __restrict__ xbf, float* __restrict__ gmax) {
    __shared__ unsigned short tile[4][64 * 66];   // 33792 B (transpose section only)
    const int bx = blockIdx.x, t = threadIdx.x;

    if (bx < 72) {                                 // ---- weight prep ----
        int tid = bx * 1024 + t;
        if (tid < 2 * WELEM) {
            const float* src = (tid < WELEM) ? w1 : w2;
            unsigned short* dst = (tid < WELEM) ? w1p : w2p;
            int e = (tid < WELEM) ? tid : tid - WELEM;
            int c  = e & 63;
            int o  = (e >> 6) & 63;
            int kk = e >> 12;                      // 0..8
            int cs = c ^ ((o & 7) << 3);           // pre-swizzle
            dst[kk * 4096 + o * 64 + cs] = f2bf(src[o * 576 + c * 9 + kk]);
        }
        return;
    }
    if (bx < 584) {                                // ---- gmax ----
        int p = (bx - 72) * 1024 + t;              // 524288 px
        int b = p >> 16, rem = p & 65535, y = rem >> 8, xx0 = rem & 255;
        const float* gb = gate + (size_t)b * 65536;
        float m = 0.f;
        #pragma unroll
        for (int dy = -1; dy <= 1; ++dy)
            #pragma unroll
            for (int dx = -1; dx <= 1; ++dx) {
                int yy = y + dy, xx = xx0 + dx;
                if ((unsigned)yy < HH && (unsigned)xx < WW)
                    m = fmaxf(m, gb[yy * 256 + xx]);
            }
        gmax[p] = m;
        return;
    }
    // ---- transpose: 2048 blocks, 4 sub-tiles each (original 256-thread logic) ----
    const int sub = t >> 8, tt = t & 255;
    const int obx = (bx - 584) * 4 + sub;          // 0..8191
    const int xt = obx & 3, y = (obx >> 2) & 255, b = obx >> 10;
    const int x0 = xt * 64;
    const float* xb = x + (size_t)b * (64 * 65536) + y * 256 + x0;
    unsigned short* tl = tile[sub];
    #pragma unroll
    for (int it = 0; it < 4; ++it) {
        int idx = it * 256 + tt;
        int c = idx >> 4, xi = (idx & 15) * 4;
        float4 v = *reinterpret_cast<const float4*>(xb + (size_t)c * 65536 + xi);
        ushort4 o;
        o.x = f2bf(v.x); o.y = f2bf(v.y); o.z = f2bf(v.z); o.w = f2bf(v.w);
        *reinterpret_cast<ushort4*>(&tl[c * 66 + xi]) = o;
    }
    __syncthreads();                               // all 4 sub-tiles in same phase
    unsigned short* ob = xbf + ((size_t)(b * 65536 + y * 256 + x0)) * 64;
    #pragma unroll
    for (int it = 0; it < 2; ++it) {
        int idx = it * 256 + tt;
        int pix = idx >> 3, cg = idx & 7;
        unsigned short tmp[8];
        #pragma unroll
        for (int j = 0; j < 8; ++j) tmp[j] = tl[(cg * 8 + j) * 66 + pix];
        *reinterpret_cast<uint4*>(ob + (size_t)pix * 64 + cg * 8) = *reinterpret_cast<uint4*>(tmp);
    }
}

// ---------------- conv1: r8 body + LDS-bounce epilogue + XCD=batch swizzle ----------------
__global__ __launch_bounds__(1024, 1)
void conv1_kernel(const unsigned short* __restrict__ xbf, const float* __restrict__ gmaxg,
                  const unsigned short* __restrict__ wp,
                  const float* __restrict__ scale1, const float* __restrict__ bias1,
                  unsigned short* __restrict__ h) {
    __shared__ __align__(16) unsigned short patch[NPIX * 64];  // 78336 B
    __shared__ __align__(16) unsigned short wlds[WELEM];       // 73728 B

    const int tid = threadIdx.x;
    const int bx0 = blockIdx.x;
    const int bx  = ((bx0 & 7) << 7) | (bx0 >> 3); // XCD k -> batch k (1024 = 8*128)
    const int txi = bx & 7, tyi = (bx >> 3) & 15, b = bx >> 7;
    const int x0 = txi * TW, y0 = tyi * TH;

    char* pb = (char*)patch;
    char* wb = (char*)wlds;

    #pragma unroll
    for (int i = 0; i < 5; ++i) {
        int s = tid + i * 1024;
        if (s < WELEM / 8)
            gl16((const char*)wp + s * 16, wb + s * 16);
    }
    const unsigned short* hbase = xbf + (size_t)b * (65536 * 64);
    #pragma unroll
    for (int i = 0; i < 5; ++i) {
        int s = tid + i * 1024;
        if (s < NPIX * 8) {
            int p = s >> 3, j = s & 7;
            int row = p / PW, px = p - row * PW;
            int y = y0 - 1 + row, xg = x0 - 1 + px;
            bool valid = (unsigned)y < HH && (unsigned)xg < WW;
            int cc = j ^ (p & 7);
            size_t goff = valid ? ((size_t)(y * 256 + xg) * 64 + cc * 8) : 0;
            gl16(hbase + goff, pb + s * 16);
        }
    }
    __syncthreads();
    #pragma unroll
    for (int i = 0; i < 5; ++i) {
        int s = tid + i * 1024;
        if (s < NPIX * 8) {
            int p = s >> 3;
            int row = p / PW, px = p - row * PW;
            int y = y0 - 1 + row, xg = x0 - 1 + px;
            if (!((unsigned)y < HH && (unsigned)xg < WW))
                *reinterpret_cast<uint4*>(pb + s * 16) = make_uint4(0u, 0u, 0u, 0u);
        }
    }
    __syncthreads();

    const int w = tid >> 6, l = tid & 63;
    const int l15 = l & 15, lq = l >> 4;

    float4v acc[2][4];
    #pragma unroll
    for (int m = 0; m < 2; ++m)
        #pragma unroll
        for (int n = 0; n < 4; ++n)
            acc[m][n] = (float4v){0.f, 0.f, 0.f, 0.f};

    #pragma unroll
    for (int kk = 0; kk < 9; ++kk) {
        const int ky = kk / 3, kx = kk - ky * 3;
        #pragma unroll
        for (int kc = 0; kc < 2; ++kc) {
            const int kbyte = kc * 64 + lq * 16;
            short8 a0 = *reinterpret_cast<const short8*>(pb + swz(((w + ky) * PW + l15 + kx) * 128 + kbyte));
            short8 a1 = *reinterpret_cast<const short8*>(pb + swz(((w + ky) * PW + 16 + l15 + kx) * 128 + kbyte));
            #pragma unroll
            for (int nt = 0; nt < 4; ++nt) {
                short8 bf = *reinterpret_cast<const short8*>(wb + swz((kk * 64 + nt * 16 + l15) * 128 + kbyte));
                acc[0][nt] = __builtin_amdgcn_mfma_f32_16x16x32_bf16(a0, bf, acc[0][nt], 0, 0, 0);
                acc[1][nt] = __builtin_amdgcn_mfma_f32_16x16x32_bf16(a1, bf, acc[1][nt], 0, 0, 0);
            }
        }
    }

    // epilogue: BN1 + ReLU + *gmax -> LDS bounce (patch is dead) -> dense 16B stores
    float s1v[4], b1v[4];
    #pragma unroll
    for (int nt = 0; nt < 4; ++nt) {
        s1v[nt] = scale1[nt * 16 + l15];
        b1v[nt] = bias1[nt * 16 + l15];
    }
    const int y = y0 + w;
    const float* gm = gmaxg + (size_t)b * 65536 + y * 256;
    __syncthreads();                           // all patch reads done; safe to reuse
    unsigned short* tb = patch;                // [512 px][64 c] bf16, linear (65536 B)
    #pragma unroll
    for (int m = 0; m < 2; ++m)
        #pragma unroll
        for (int r = 0; r < 4; ++r) {
            int px = m * 16 + lq * 4 + r;
            float g = gm[x0 + px];
            int pixl = (w << 5) + px;          // row w, col px
            #pragma unroll
            for (int nt = 0; nt < 4; ++nt) {
                float v = acc[m][nt][r] * s1v[nt] + b1v[nt];
                v = fmaxf(v, 0.f) * g;
                tb[pixl * 64 + nt * 16 + l15] = f2bf(v);
            }
        }
    __syncthreads();
    // dense coalesced write: 4096 uint4, 4/thread, 1KB contiguous per wave-instruction
    unsigned short* hball = h + (size_t)b * 65536 * 64;
    #pragma unroll
    for (int i = 0; i < 4; ++i) {
        int s = tid + i * 1024;
        int pix = s >> 3, part = s & 7;
        int yy = y0 + (pix >> 5), xx = x0 + (pix & 31);
        *reinterpret_cast<uint4*>(hball + (size_t)(yy * 256 + xx) * 64 + part * 8) =
            *reinterpret_cast<const uint4*>(tb + pix * 64 + part * 8);
    }
}

// ---------------- conv1 fallback (ws too small): round-8 version unchanged ----------------
__global__ __launch_bounds__(1024, 1)
void conv1_fallback(const float* __restrict__ x, const float* __restrict__ gate,
                    const unsigned short* __restrict__ wp,
                    const float* __restrict__ scale1, const float* __restrict__ bias1,
                    unsigned short* __restrict__ h) {
    __shared__ __align__(16) unsigned short patch[NPIX * 64];
    __shared__ __align__(16) unsigned short wlds[WELEM];
    __shared__ float gpatch[NPIX];
    __shared__ float gmax[TH * TW];

    const int tid = threadIdx.x;
    const int bx  = blockIdx.x;
    const int txi = bx & 7, tyi = (bx >> 3) & 15, b = bx >> 7;
    const int x0 = txi * TW, y0 = tyi * TH;

    char* pb = (char*)patch;
    char* wb = (char*)wlds;

    const float* xb = x + (size_t)b * (64 * 65536);
    for (int e = tid; e < NPIX * 64; e += 1024) {
        int c  = e / NPIX;
        int rp = e - c * NPIX;
        int row = rp / PW;
        int px  = rp - row * PW;
        int y = y0 - 1 + row, xg = x0 - 1 + px;
        float v = 0.f;
        if ((unsigned)y < HH && (unsigned)xg < WW)
            v = xb[(size_t)c * 65536 + y * 256 + xg];
        *reinterpret_cast<unsigned short*>(pb + swz(rp * 128 + c * 2)) = f2bf(v);
    }
    const float* gb = gate + (size_t)b * 65536;
    for (int e = tid; e < NPIX; e += 1024) {
        int row = e / PW, px = e - row * PW;
        int y = y0 - 1 + row, xg = x0 - 1 + px;
        gpatch[e] = ((unsigned)y < HH && (unsigned)xg < WW) ? gb[y * 256 + xg] : 0.f;
    }
    for (int s = tid; s < WELEM / 8; s += 1024) {
        *reinterpret_cast<uint4*>(wb + s * 16) =
            *reinterpret_cast<const uint4*>((const char*)wp + s * 16);
    }
    __syncthreads();

    if (tid < TH * TW) {
        int r = tid >> 5, px = tid & 31;
        float m = 0.f;
        #pragma unroll
        for (int dy = 0; dy < 3; ++dy)
            #pragma unroll
            for (int dx = 0; dx < 3; ++dx)
                m = fmaxf(m, gpatch[(r + dy) * PW + px + dx]);
        gmax[tid] = m;
    }
    __syncthreads();

    const int w = tid >> 6, l = tid & 63;
    const int l15 = l & 15, lq = l >> 4;

    float4v acc[2][4];
    #pragma unroll
    for (int m = 0; m < 2; ++m)
        #pragma unroll
        for (int n = 0; n < 4; ++n)
            acc[m][n] = (float4v){0.f, 0.f, 0.f, 0.f};

    #pragma unroll
    for (int kk = 0; kk < 9; ++kk) {
        const int ky = kk / 3, kx = kk - ky * 3;
        #pragma unroll
        for (int kc = 0; kc < 2; ++kc) {
            const int kbyte = kc * 64 + lq * 16;
            short8 a0 = *reinterpret_cast<const short8*>(pb + swz(((w + ky) * PW + l15 + kx) * 128 + kbyte));
            short8 a1 = *reinterpret_cast<const short8*>(pb + swz(((w + ky) * PW + 16 + l15 + kx) * 128 + kbyte));
            #pragma unroll
            for (int nt = 0; nt < 4; ++nt) {
                short8 bf = *reinterpret_cast<const short8*>(wb + swz((kk * 64 + nt * 16 + l15) * 128 + kbyte));
                acc[0][nt] = __builtin_amdgcn_mfma_f32_16x16x32_bf16(a0, bf, acc[0][nt], 0, 0, 0);
                acc[1][nt] = __builtin_amdgcn_mfma_f32_16x16x32_bf16(a1, bf, acc[1][nt], 0, 0, 0);
            }
        }
    }

    float s1v[4], b1v[4];
    #pragma unroll
    for (int nt = 0; nt < 4; ++nt) {
        s1v[nt] = scale1[nt * 16 + l15];
        b1v[nt] = bias1[nt * 16 + l15];
    }
    const int y = y0 + w;
    unsigned short* hb = h + ((size_t)b * 65536 + (size_t)y * 256) * 64;
    #pragma unroll
    for (int m = 0; m < 2; ++m)
        #pragma unroll
        for (int r = 0; r < 4; ++r) {
            int px = m * 16 + lq * 4 + r;
            float g = gmax[w * 32 + px];
            #pragma unroll
            for (int nt = 0; nt < 4; ++nt) {
                float v = acc[m][nt][r] * s1v[nt] + b1v[nt];
                v = fmaxf(v, 0.f) * g;
                hb[(size_t)(x0 + px) * 64 + nt * 16 + l15] = f2bf(v);
            }
        }
}

// ---------------- conv2 (round-12 body + XCD=batch swizzle) ----------------
__global__ __launch_bounds__(1024, 1)
void conv2_kernel(const unsigned short* __restrict__ h, const float* __restrict__ x,
                  const unsigned short* __restrict__ xr16,
                  const float* __restrict__ gate, const unsigned short* __restrict__ wp,
                  const float* __restrict__ scale2, const float* __restrict__ bias2,
                  float* __restrict__ out) {
    __shared__ __align__(16) unsigned short patch[NPIX * 64];
    __shared__ __align__(16) unsigned short wlds[WELEM];

    const int tid = threadIdx.x;
    const int bx0 = blockIdx.x;
    const int bx  = ((bx0 & 7) << 7) | (bx0 >> 3); // XCD k -> batch k
    const int txi = bx & 7, tyi = (bx >> 3) & 15, b = bx >> 7;
    const int x0 = txi * TW, y0 = tyi * TH;

    char* pb = (char*)patch;
    char* wb = (char*)wlds;

    #pragma unroll
    for (int i = 0; i < 5; ++i) {
        int s = tid + i * 1024;
        if (s < WELEM / 8)
            gl16((const char*)wp + s * 16, wb + s * 16);
    }
    const unsigned short* hbase = h + (size_t)b * (65536 * 64);
    #pragma unroll
    for (int i = 0; i < 5; ++i) {
        int s = tid + i * 1024;
        if (s < NPIX * 8) {
            int p = s >> 3, j = s & 7;
            int row = p / PW, px = p - row * PW;
            int y = y0 - 1 + row, xg = x0 - 1 + px;
            bool valid = (unsigned)y < HH && (unsigned)xg < WW;
            int cc = j ^ (p & 7);
            size_t goff = valid ? ((size_t)(y * 256 + xg) * 64 + cc * 8) : 0;
            gl16(hbase + goff, pb + s * 16);
        }
    }
    __syncthreads();
    #pragma unroll
    for (int i = 0; i < 5; ++i) {
        int s = tid + i * 1024;
        if (s < NPIX * 8) {
            int p = s >> 3;
            int row = p / PW, px = p - row * PW;
            int y = y0 - 1 + row, xg = x0 - 1 + px;
            if (!((unsigned)y < HH && (unsigned)xg < WW))
                *reinterpret_cast<uint4*>(pb + s * 16) = make_uint4(0u, 0u, 0u, 0u);
        }
    }
    __syncthreads();

    const int w = tid >> 6, l = tid & 63;      // 16 waves, wave = output row
    const int l15 = l & 15, lq = l >> 4;

    float4v acc[4][2];                         // [oc-frag][px-half]
    #pragma unroll
    for (int m = 0; m < 4; ++m)
        #pragma unroll
        for (int n = 0; n < 2; ++n)
            acc[m][n] = (float4v){0.f, 0.f, 0.f, 0.f};

    #pragma unroll
    for (int kk = 0; kk < 9; ++kk) {
        const int ky = kk / 3, kx = kk - ky * 3;
        #pragma unroll
        for (int kc = 0; kc < 2; ++kc) {
            const int kbyte = kc * 64 + lq * 16;
            short8 bp0 = *reinterpret_cast<const short8*>(pb + swz(((w + ky) * PW + l15 + kx) * 128 + kbyte));
            short8 bp1 = *reinterpret_cast<const short8*>(pb + swz(((w + ky) * PW + 16 + l15 + kx) * 128 + kbyte));
            #pragma unroll
            for (int mt = 0; mt < 4; ++mt) {
                short8 aw = *reinterpret_cast<const short8*>(wb + swz((kk * 64 + mt * 16 + l15) * 128 + kbyte));
                acc[mt][0] = __builtin_amdgcn_mfma_f32_16x16x32_bf16(aw, bp0, acc[mt][0], 0, 0, 0);
                acc[mt][1] = __builtin_amdgcn_mfma_f32_16x16x32_bf16(aw, bp1, acc[mt][1], 0, 0, 0);
            }
        }
    }

    // epilogue: BN2 + *gate + residual + ReLU, store NCHW f32 (coalesced: l15 = px)
    const int y = y0 + w;
    const float* gr = gate + (size_t)b * 65536 + y * 256 + x0;
    float g0 = gr[l15], g1 = gr[16 + l15];
    #pragma unroll
    for (int mt = 0; mt < 4; ++mt) {
        float sc4[4], bi4[4];
        #pragma unroll
        for (int r = 0; r < 4; ++r) {
            int oc = mt * 16 + lq * 4 + r;
            sc4[r] = scale2[oc];
            bi4[r] = bias2[oc];
        }
        #pragma unroll
        for (int nt = 0; nt < 2; ++nt) {
            int px = nt * 16 + l15;
            float g = nt ? g1 : g0;
            float xv[4];
            if (xr16) {
                // residual from bf16 NHWC copy: 4 consecutive oc = one ushort4
                size_t pix = (size_t)b * 65536 + (size_t)y * 256 + x0 + px;
                ushort4 u = *reinterpret_cast<const ushort4*>(xr16 + pix * 64 + mt * 16 + lq * 4);
                xv[0] = bf2f(u.x); xv[1] = bf2f(u.y); xv[2] = bf2f(u.z); xv[3] = bf2f(u.w);
            } else {
                #pragma unroll
                for (int r = 0; r < 4; ++r) {
                    int oc = mt * 16 + lq * 4 + r;
                    xv[r] = x[((size_t)(b * 64 + oc) * 256 + y) * 256 + x0 + px];
                }
            }
            #pragma unroll
            for (int r = 0; r < 4; ++r) {
                int oc = mt * 16 + lq * 4 + r;
                size_t base = ((size_t)(b * 64 + oc) * 256 + y) * 256 + x0;
                float v = acc[mt][nt][r] * sc4[r] + bi4[r];
                v = v * g + xv[r];
                out[base + px] = fmaxf(v, 0.f);
            }
        }
    }
}

extern "C" void kernel_launch(void* const* d_in, const int* in_sizes, int n_in,
                              void* d_out, int out_size, void* d_ws, size_t ws_size,
                              hipStream_t stream) {
    const float* x      = (const float*)d_in[0];
    const float* gate   = (const float*)d_in[1];
    const float* w1     = (const float*)d_in[2];
    const float* scale1 = (const float*)d_in[3];
    const float* bias1  = (const float*)d_in[4];
    const float* w2     = (const float*)d_in[5];
    const float* scale2 = (const float*)d_in[6];
    const float* bias2  = (const float*)d_in[7];
    float* out = (float*)d_out;

    char* ws = (char*)d_ws;
    const size_t HBYTES = 67108864;            // 64 MiB NHWC bf16 h
    const size_t NEED_BIG = 2 * HBYTES + 2 * 73728;

    // gmax (3x3 maxpool of gate) lives in `out` as scratch: consumed only by conv1,
    // then conv2 fully overwrites out (stream-ordered). Proven rounds 5-12.
    float* gmaxbuf = out;

    if (ws_size >= NEED_BIG) {
        unsigned short* hbuf = (unsigned short*)ws;
        unsigned short* xbf  = (unsigned short*)(ws + HBYTES);
        unsigned short* w1p  = (unsigned short*)(ws + 2 * HBYTES);
        unsigned short* w2p  = (unsigned short*)(ws + 2 * HBYTES + 73728);
        prep_all<<<2632, 1024, 0, stream>>>(w1, w2, x, gate, w1p, w2p, xbf, gmaxbuf);
        conv1_kernel<<<1024, 1024, 0, stream>>>(xbf, gmaxbuf, w1p, scale1, bias1, hbuf);
        conv2_kernel<<<1024, 1024, 0, stream>>>(hbuf, x, xbf, gate, w2p, scale2, bias2, out);
    } else {
        unsigned short* hbuf = (unsigned short*)ws;
        unsigned short* w1p  = (unsigned short*)(ws + HBYTES);
        unsigned short* w2p  = (unsigned short*)(ws + HBYTES + 73728);
        // fallback: only the 72 weight-prep blocks (no gmax/transpose sections launched)
        prep_all<<<72, 1024, 0, stream>>>(w1, w2, x, gate, w1p, w2p, nullptr, nullptr);
        conv1_fallback<<<1024, 1024, 0, stream>>>(x, gate, w1p, scale1, bias1, hbuf);
        conv2_kernel<<<1024, 1024, 0, stream>>>(hbuf, x, nullptr, gate, w2p, scale2, bias2, out);
    }
}

// Round 14
// 145.810 us; speedup vs baseline: 1.0906x; 1.0906x over previous
//
#include <hip/hip_runtime.h>
#include <hip/hip_bf16.h>
#include <stdint.h>

#define BATCH 8
#define CH    64
#define HH    256
#define WW    256
#define TW    32
#define TH    16
#define PW    34          // TW+2
#define PH    18          // TH+2
#define NPIX  (PH*PW)     // 612
#define WELEM 36864       // 9*64*64

typedef __attribute__((ext_vector_type(8))) short short8;
typedef __attribute__((ext_vector_type(4))) float float4v;
typedef __attribute__((ext_vector_type(4))) float f32x4;

__device__ __forceinline__ int swz(int byte) {
    // 128B-row XOR swizzle — proven 0-conflict (rounds 0-13) for 16B fragment reads
    return byte ^ (((byte >> 7) & 7) << 4);
}

__device__ __forceinline__ unsigned short f2bf(float v) {
    __hip_bfloat16 h = __float2bfloat16(v);
    return *reinterpret_cast<unsigned short*>(&h);
}

__device__ __forceinline__ float bf2f(unsigned short u) {
    unsigned int x = ((unsigned int)u) << 16;
    return *reinterpret_cast<float*>(&x);
}

// async global->LDS, 16B per lane; zero VGPR cost.
// CONTRACT (m104/m108): LDS dest = readfirstlane(base) + lane*16. Only call with
// full-wave or lane-0-anchored-prefix exec and per-lane-linear lds addresses.
__device__ __forceinline__ void gl16(const void* g, void* l) {
    __builtin_amdgcn_global_load_lds(
        (const __attribute__((address_space(1))) unsigned int*)g,
        (__attribute__((address_space(3))) unsigned int*)l, 16, 0, 0);
}

// ---------------- fused prep: weights + gmax + transpose in ONE launch ----------------
// blocks [0,72):    weight prep  f32 OIHW -> bf16 [kk][o][c] PRE-SWIZZLED
// blocks [72,584):  gmax 3x3 maxpool of gate -> gmax image (scratch in `out`)
// blocks [584,2632): transpose x NCHW f32 -> xbf NHWC bf16 (4 tiles per block)
__global__ __launch_bounds__(1024)
void prep_all(const float* __restrict__ w1, const float* __restrict__ w2,
              const float* __restrict__ x, const float* __restrict__ gate,
              unsigned short* __restrict__ w1p, unsigned short* __restrict__ w2p,
              unsigned short* __restrict__ xbf, float* __restrict__ gmax) {
    __shared__ unsigned short tile[4][64 * 66];   // 33792 B (transpose section only)
    const int bx = blockIdx.x, t = threadIdx.x;

    if (bx < 72) {                                 // ---- weight prep ----
        int tid = bx * 1024 + t;
        if (tid < 2 * WELEM) {
            const float* src = (tid < WELEM) ? w1 : w2;
            unsigned short* dst = (tid < WELEM) ? w1p : w2p;
            int e = (tid < WELEM) ? tid : tid - WELEM;
            int c  = e & 63;
            int o  = (e >> 6) & 63;
            int kk = e >> 12;                      // 0..8
            int cs = c ^ ((o & 7) << 3);           // pre-swizzle
            dst[kk * 4096 + o * 64 + cs] = f2bf(src[o * 576 + c * 9 + kk]);
        }
        return;
    }
    if (bx < 584) {                                // ---- gmax ----
        int p = (bx - 72) * 1024 + t;              // 524288 px
        int b = p >> 16, rem = p & 65535, y = rem >> 8, xx0 = rem & 255;
        const float* gb = gate + (size_t)b * 65536;
        float m = 0.f;
        #pragma unroll
        for (int dy = -1; dy <= 1; ++dy)
            #pragma unroll
            for (int dx = -1; dx <= 1; ++dx) {
                int yy = y + dy, xx = xx0 + dx;
                if ((unsigned)yy < HH && (unsigned)xx < WW)
                    m = fmaxf(m, gb[yy * 256 + xx]);
            }
        gmax[p] = m;
        return;
    }
    // ---- transpose: 2048 blocks, 4 sub-tiles each; NON-TEMPORAL x loads ----
    // x is read exactly once in the whole pipeline: keep it out of L2/L3 so
    // xbf + h (reused by conv1/conv2) stay resident.
    const int sub = t >> 8, tt = t & 255;
    const int obx = (bx - 584) * 4 + sub;          // 0..8191
    const int xt = obx & 3, y = (obx >> 2) & 255, b = obx >> 10;
    const int x0 = xt * 64;
    const float* xb = x + (size_t)b * (64 * 65536) + y * 256 + x0;
    unsigned short* tl = tile[sub];
    #pragma unroll
    for (int it = 0; it < 4; ++it) {
        int idx = it * 256 + tt;
        int c = idx >> 4, xi = (idx & 15) * 4;
        f32x4 v = __builtin_nontemporal_load(
            reinterpret_cast<const f32x4*>(xb + (size_t)c * 65536 + xi));
        ushort4 o;
        o.x = f2bf(v[0]); o.y = f2bf(v[1]); o.z = f2bf(v[2]); o.w = f2bf(v[3]);
        *reinterpret_cast<ushort4*>(&tl[c * 66 + xi]) = o;
    }
    __syncthreads();                               // all 4 sub-tiles in same phase
    unsigned short* ob = xbf + ((size_t)(b * 65536 + y * 256 + x0)) * 64;
    #pragma unroll
    for (int it = 0; it < 2; ++it) {
        int idx = it * 256 + tt;
        int pix = idx >> 3, cg = idx & 7;
        unsigned short tmp[8];
        #pragma unroll
        for (int j = 0; j < 8; ++j) tmp[j] = tl[(cg * 8 + j) * 66 + pix];
        *reinterpret_cast<uint4*>(ob + (size_t)pix * 64 + cg * 8) = *reinterpret_cast<uint4*>(tmp);
    }
}

// ---------------- conv1 (round-8/12 champion, unchanged): xbf -> h ----------------
__global__ __launch_bounds__(1024, 1)
void conv1_kernel(const unsigned short* __restrict__ xbf, const float* __restrict__ gmaxg,
                  const unsigned short* __restrict__ wp,
                  const float* __restrict__ scale1, const float* __restrict__ bias1,
                  unsigned short* __restrict__ h) {
    __shared__ __align__(16) unsigned short patch[NPIX * 64];  // 78336 B
    __shared__ __align__(16) unsigned short wlds[WELEM];       // 73728 B

    const int tid = threadIdx.x;
    const int bx  = blockIdx.x;                // 1024 = 8 tx * 16 ty * 8 b
    const int txi = bx & 7, tyi = (bx >> 3) & 15, b = bx >> 7;
    const int x0 = txi * TW, y0 = tyi * TH;

    char* pb = (char*)patch;
    char* wb = (char*)wlds;

    #pragma unroll
    for (int i = 0; i < 5; ++i) {
        int s = tid + i * 1024;
        if (s < WELEM / 8)
            gl16((const char*)wp + s * 16, wb + s * 16);
    }
    const unsigned short* hbase = xbf + (size_t)b * (65536 * 64);
    #pragma unroll
    for (int i = 0; i < 5; ++i) {
        int s = tid + i * 1024;
        if (s < NPIX * 8) {
            int p = s >> 3, j = s & 7;
            int row = p / PW, px = p - row * PW;
            int y = y0 - 1 + row, xg = x0 - 1 + px;
            bool valid = (unsigned)y < HH && (unsigned)xg < WW;
            int cc = j ^ (p & 7);
            size_t goff = valid ? ((size_t)(y * 256 + xg) * 64 + cc * 8) : 0;
            gl16(hbase + goff, pb + s * 16);
        }
    }
    __syncthreads();
    #pragma unroll
    for (int i = 0; i < 5; ++i) {
        int s = tid + i * 1024;
        if (s < NPIX * 8) {
            int p = s >> 3;
            int row = p / PW, px = p - row * PW;
            int y = y0 - 1 + row, xg = x0 - 1 + px;
            if (!((unsigned)y < HH && (unsigned)xg < WW))
                *reinterpret_cast<uint4*>(pb + s * 16) = make_uint4(0u, 0u, 0u, 0u);
        }
    }
    __syncthreads();

    const int w = tid >> 6, l = tid & 63;
    const int l15 = l & 15, lq = l >> 4;

    float4v acc[2][4];
    #pragma unroll
    for (int m = 0; m < 2; ++m)
        #pragma unroll
        for (int n = 0; n < 4; ++n)
            acc[m][n] = (float4v){0.f, 0.f, 0.f, 0.f};

    #pragma unroll
    for (int kk = 0; kk < 9; ++kk) {
        const int ky = kk / 3, kx = kk - ky * 3;
        #pragma unroll
        for (int kc = 0; kc < 2; ++kc) {
            const int kbyte = kc * 64 + lq * 16;
            short8 a0 = *reinterpret_cast<const short8*>(pb + swz(((w + ky) * PW + l15 + kx) * 128 + kbyte));
            short8 a1 = *reinterpret_cast<const short8*>(pb + swz(((w + ky) * PW + 16 + l15 + kx) * 128 + kbyte));
            #pragma unroll
            for (int nt = 0; nt < 4; ++nt) {
                short8 bf = *reinterpret_cast<const short8*>(wb + swz((kk * 64 + nt * 16 + l15) * 128 + kbyte));
                acc[0][nt] = __builtin_amdgcn_mfma_f32_16x16x32_bf16(a0, bf, acc[0][nt], 0, 0, 0);
                acc[1][nt] = __builtin_amdgcn_mfma_f32_16x16x32_bf16(a1, bf, acc[1][nt], 0, 0, 0);
            }
        }
    }

    float s1v[4], b1v[4];
    #pragma unroll
    for (int nt = 0; nt < 4; ++nt) {
        s1v[nt] = scale1[nt * 16 + l15];
        b1v[nt] = bias1[nt * 16 + l15];
    }
    const int y = y0 + w;
    const float* gm = gmaxg + (size_t)b * 65536 + y * 256;
    unsigned short* hb = h + ((size_t)b * 65536 + (size_t)y * 256) * 64;
    #pragma unroll
    for (int m = 0; m < 2; ++m)
        #pragma unroll
        for (int r = 0; r < 4; ++r) {
            int px = m * 16 + lq * 4 + r;
            float g = gm[x0 + px];
            #pragma unroll
            for (int nt = 0; nt < 4; ++nt) {
                float v = acc[m][nt][r] * s1v[nt] + b1v[nt];
                v = fmaxf(v, 0.f) * g;
                hb[(size_t)(x0 + px) * 64 + nt * 16 + l15] = f2bf(v);
            }
        }
}

// ---------------- conv1 fallback (ws too small): round-8 version unchanged ----------------
__global__ __launch_bounds__(1024, 1)
void conv1_fallback(const float* __restrict__ x, const float* __restrict__ gate,
                    const unsigned short* __restrict__ wp,
                    const float* __restrict__ scale1, const float* __restrict__ bias1,
                    unsigned short* __restrict__ h) {
    __shared__ __align__(16) unsigned short patch[NPIX * 64];
    __shared__ __align__(16) unsigned short wlds[WELEM];
    __shared__ float gpatch[NPIX];
    __shared__ float gmax[TH * TW];

    const int tid = threadIdx.x;
    const int bx  = blockIdx.x;
    const int txi = bx & 7, tyi = (bx >> 3) & 15, b = bx >> 7;
    const int x0 = txi * TW, y0 = tyi * TH;

    char* pb = (char*)patch;
    char* wb = (char*)wlds;

    const float* xb = x + (size_t)b * (64 * 65536);
    for (int e = tid; e < NPIX * 64; e += 1024) {
        int c  = e / NPIX;
        int rp = e - c * NPIX;
        int row = rp / PW;
        int px  = rp - row * PW;
        int y = y0 - 1 + row, xg = x0 - 1 + px;
        float v = 0.f;
        if ((unsigned)y < HH && (unsigned)xg < WW)
            v = xb[(size_t)c * 65536 + y * 256 + xg];
        *reinterpret_cast<unsigned short*>(pb + swz(rp * 128 + c * 2)) = f2bf(v);
    }
    const float* gb = gate + (size_t)b * 65536;
    for (int e = tid; e < NPIX; e += 1024) {
        int row = e / PW, px = e - row * PW;
        int y = y0 - 1 + row, xg = x0 - 1 + px;
        gpatch[e] = ((unsigned)y < HH && (unsigned)xg < WW) ? gb[y * 256 + xg] : 0.f;
    }
    for (int s = tid; s < WELEM / 8; s += 1024) {
        *reinterpret_cast<uint4*>(wb + s * 16) =
            *reinterpret_cast<const uint4*>((const char*)wp + s * 16);
    }
    __syncthreads();

    if (tid < TH * TW) {
        int r = tid >> 5, px = tid & 31;
        float m = 0.f;
        #pragma unroll
        for (int dy = 0; dy < 3; ++dy)
            #pragma unroll
            for (int dx = 0; dx < 3; ++dx)
                m = fmaxf(m, gpatch[(r + dy) * PW + px + dx]);
        gmax[tid] = m;
    }
    __syncthreads();

    const int w = tid >> 6, l = tid & 63;
    const int l15 = l & 15, lq = l >> 4;

    float4v acc[2][4];
    #pragma unroll
    for (int m = 0; m < 2; ++m)
        #pragma unroll
        for (int n = 0; n < 4; ++n)
            acc[m][n] = (float4v){0.f, 0.f, 0.f, 0.f};

    #pragma unroll
    for (int kk = 0; kk < 9; ++kk) {
        const int ky = kk / 3, kx = kk - ky * 3;
        #pragma unroll
        for (int kc = 0; kc < 2; ++kc) {
            const int kbyte = kc * 64 + lq * 16;
            short8 a0 = *reinterpret_cast<const short8*>(pb + swz(((w + ky) * PW + l15 + kx) * 128 + kbyte));
            short8 a1 = *reinterpret_cast<const short8*>(pb + swz(((w + ky) * PW + 16 + l15 + kx) * 128 + kbyte));
            #pragma unroll
            for (int nt = 0; nt < 4; ++nt) {
                short8 bf = *reinterpret_cast<const short8*>(wb + swz((kk * 64 + nt * 16 + l15) * 128 + kbyte));
                acc[0][nt] = __builtin_amdgcn_mfma_f32_16x16x32_bf16(a0, bf, acc[0][nt], 0, 0, 0);
                acc[1][nt] = __builtin_amdgcn_mfma_f32_16x16x32_bf16(a1, bf, acc[1][nt], 0, 0, 0);
            }
        }
    }

    float s1v[4], b1v[4];
    #pragma unroll
    for (int nt = 0; nt < 4; ++nt) {
        s1v[nt] = scale1[nt * 16 + l15];
        b1v[nt] = bias1[nt * 16 + l15];
    }
    const int y = y0 + w;
    unsigned short* hb = h + ((size_t)b * 65536 + (size_t)y * 256) * 64;
    #pragma unroll
    for (int m = 0; m < 2; ++m)
        #pragma unroll
        for (int r = 0; r < 4; ++r) {
            int px = m * 16 + lq * 4 + r;
            float g = gmax[w * 32 + px];
            #pragma unroll
            for (int nt = 0; nt < 4; ++nt) {
                float v = acc[m][nt][r] * s1v[nt] + b1v[nt];
                v = fmaxf(v, 0.f) * g;
                hb[(size_t)(x0 + px) * 64 + nt * 16 + l15] = f2bf(v);
            }
        }
}

// ---------------- conv2 (round-12 body + non-temporal out stores) ----------------
__global__ __launch_bounds__(1024, 1)
void conv2_kernel(const unsigned short* __restrict__ h, const float* __restrict__ x,
                  const unsigned short* __restrict__ xr16,
                  const float* __restrict__ gate, const unsigned short* __restrict__ wp,
                  const float* __restrict__ scale2, const float* __restrict__ bias2,
                  float* __restrict__ out) {
    __shared__ __align__(16) unsigned short patch[NPIX * 64];
    __shared__ __align__(16) unsigned short wlds[WELEM];

    const int tid = threadIdx.x;
    const int bx  = blockIdx.x;
    const int txi = bx & 7, tyi = (bx >> 3) & 15, b = bx >> 7;
    const int x0 = txi * TW, y0 = tyi * TH;

    char* pb = (char*)patch;
    char* wb = (char*)wlds;

    #pragma unroll
    for (int i = 0; i < 5; ++i) {
        int s = tid + i * 1024;
        if (s < WELEM / 8)
            gl16((const char*)wp + s * 16, wb + s * 16);
    }
    const unsigned short* hbase = h + (size_t)b * (65536 * 64);
    #pragma unroll
    for (int i = 0; i < 5; ++i) {
        int s = tid + i * 1024;
        if (s < NPIX * 8) {
            int p = s >> 3, j = s & 7;
            int row = p / PW, px = p - row * PW;
            int y = y0 - 1 + row, xg = x0 - 1 + px;
            bool valid = (unsigned)y < HH && (unsigned)xg < WW;
            int cc = j ^ (p & 7);
            size_t goff = valid ? ((size_t)(y * 256 + xg) * 64 + cc * 8) : 0;
            gl16(hbase + goff, pb + s * 16);
        }
    }
    __syncthreads();
    #pragma unroll
    for (int i = 0; i < 5; ++i) {
        int s = tid + i * 1024;
        if (s < NPIX * 8) {
            int p = s >> 3;
            int row = p / PW, px = p - row * PW;
            int y = y0 - 1 + row, xg = x0 - 1 + px;
            if (!((unsigned)y < HH && (unsigned)xg < WW))
                *reinterpret_cast<uint4*>(pb + s * 16) = make_uint4(0u, 0u, 0u, 0u);
        }
    }
    __syncthreads();

    const int w = tid >> 6, l = tid & 63;      // 16 waves, wave = output row
    const int l15 = l & 15, lq = l >> 4;

    float4v acc[4][2];                         // [oc-frag][px-half]
    #pragma unroll
    for (int m = 0; m < 4; ++m)
        #pragma unroll
        for (int n = 0; n < 2; ++n)
            acc[m][n] = (float4v){0.f, 0.f, 0.f, 0.f};

    #pragma unroll
    for (int kk = 0; kk < 9; ++kk) {
        const int ky = kk / 3, kx = kk - ky * 3;
        #pragma unroll
        for (int kc = 0; kc < 2; ++kc) {
            const int kbyte = kc * 64 + lq * 16;
            short8 bp0 = *reinterpret_cast<const short8*>(pb + swz(((w + ky) * PW + l15 + kx) * 128 + kbyte));
            short8 bp1 = *reinterpret_cast<const short8*>(pb + swz(((w + ky) * PW + 16 + l15 + kx) * 128 + kbyte));
            #pragma unroll
            for (int mt = 0; mt < 4; ++mt) {
                short8 aw = *reinterpret_cast<const short8*>(wb + swz((kk * 64 + mt * 16 + l15) * 128 + kbyte));
                acc[mt][0] = __builtin_amdgcn_mfma_f32_16x16x32_bf16(aw, bp0, acc[mt][0], 0, 0, 0);
                acc[mt][1] = __builtin_amdgcn_mfma_f32_16x16x32_bf16(aw, bp1, acc[mt][1], 0, 0, 0);
            }
        }
    }

    // epilogue: BN2 + *gate + residual + ReLU, NON-TEMPORAL NCHW f32 stores
    // (out is write-only, never re-read: keep its 134 MB out of L2/L3)
    const int y = y0 + w;
    const float* gr = gate + (size_t)b * 65536 + y * 256 + x0;
    float g0 = gr[l15], g1 = gr[16 + l15];
    #pragma unroll
    for (int mt = 0; mt < 4; ++mt) {
        float sc4[4], bi4[4];
        #pragma unroll
        for (int r = 0; r < 4; ++r) {
            int oc = mt * 16 + lq * 4 + r;
            sc4[r] = scale2[oc];
            bi4[r] = bias2[oc];
        }
        #pragma unroll
        for (int nt = 0; nt < 2; ++nt) {
            int px = nt * 16 + l15;
            float g = nt ? g1 : g0;
            float xv[4];
            if (xr16) {
                // residual from bf16 NHWC copy: 4 consecutive oc = one ushort4
                size_t pix = (size_t)b * 65536 + (size_t)y * 256 + x0 + px;
                ushort4 u = *reinterpret_cast<const ushort4*>(xr16 + pix * 64 + mt * 16 + lq * 4);
                xv[0] = bf2f(u.x); xv[1] = bf2f(u.y); xv[2] = bf2f(u.z); xv[3] = bf2f(u.w);
            } else {
                #pragma unroll
                for (int r = 0; r < 4; ++r) {
                    int oc = mt * 16 + lq * 4 + r;
                    xv[r] = x[((size_t)(b * 64 + oc) * 256 + y) * 256 + x0 + px];
                }
            }
            #pragma unroll
            for (int r = 0; r < 4; ++r) {
                int oc = mt * 16 + lq * 4 + r;
                size_t base = ((size_t)(b * 64 + oc) * 256 + y) * 256 + x0;
                float v = acc[mt][nt][r] * sc4[r] + bi4[r];
                v = v * g + xv[r];
                __builtin_nontemporal_store(fmaxf(v, 0.f), &out[base + px]);
            }
        }
    }
}

extern "C" void kernel_launch(void* const* d_in, const int* in_sizes, int n_in,
                              void* d_out, int out_size, void* d_ws, size_t ws_size,
                              hipStream_t stream) {
    const float* x      = (const float*)d_in[0];
    const float* gate   = (const float*)d_in[1];
    const float* w1     = (const float*)d_in[2];
    const float* scale1 = (const float*)d_in[3];
    const float* bias1  = (const float*)d_in[4];
    const float* w2     = (const float*)d_in[5];
    const float* scale2 = (const float*)d_in[6];
    const float* bias2  = (const float*)d_in[7];
    float* out = (float*)d_out;

    char* ws = (char*)d_ws;
    const size_t HBYTES = 67108864;            // 64 MiB NHWC bf16 h
    const size_t NEED_BIG = 2 * HBYTES + 2 * 73728;

    // gmax (3x3 maxpool of gate) lives in `out` as scratch: consumed only by conv1,
    // then conv2 fully overwrites out (stream-ordered). Proven rounds 5-13.
    float* gmaxbuf = out;

    if (ws_size >= NEED_BIG) {
        unsigned short* hbuf = (unsigned short*)ws;
        unsigned short* xbf  = (unsigned short*)(ws + HBYTES);
        unsigned short* w1p  = (unsigned short*)(ws + 2 * HBYTES);
        unsigned short* w2p  = (unsigned short*)(ws + 2 * HBYTES + 73728);
        prep_all<<<2632, 1024, 0, stream>>>(w1, w2, x, gate, w1p, w2p, xbf, gmaxbuf);
        conv1_kernel<<<1024, 1024, 0, stream>>>(xbf, gmaxbuf, w1p, scale1, bias1, hbuf);
        conv2_kernel<<<1024, 1024, 0, stream>>>(hbuf, x, xbf, gate, w2p, scale2, bias2, out);
    } else {
        unsigned short* hbuf = (unsigned short*)ws;
        unsigned short* w1p  = (unsigned short*)(ws + HBYTES);
        unsigned short* w2p  = (unsigned short*)(ws + HBYTES + 73728);
        // fallback: only the 72 weight-prep blocks (no gmax/transpose sections launched)
        prep_all<<<72, 1024, 0, stream>>>(w1, w2, x, gate, w1p, w2p, nullptr, nullptr);
        conv1_fallback<<<1024, 1024, 0, stream>>>(x, gate, w1p, scale1, bias1, hbuf);
        conv2_kernel<<<1024, 1024, 0, stream>>>(hbuf, x, nullptr, gate, w2p, scale2, bias2, out);
    }
}

// Round 15
// 143.413 us; speedup vs baseline: 1.1088x; 1.0167x over previous
//
#include <hip/hip_runtime.h>
#include <hip/hip_bf16.h>
#include <stdint.h>

#define BATCH 8
#define CH    64
#define HH    256
#define WW    256
#define TW    32
#define TH    16
#define PW    34          // TW+2
#define PH    18          // TH+2
#define NPIX  (PH*PW)     // 612
#define WELEM 36864       // 9*64*64

typedef __attribute__((ext_vector_type(8))) short short8;
typedef __attribute__((ext_vector_type(4))) float float4v;
typedef __attribute__((ext_vector_type(4))) float f32x4;

__device__ __forceinline__ int swz(int byte) {
    // 128B-row XOR swizzle — proven 0-conflict (rounds 0-14) for 16B fragment reads
    return byte ^ (((byte >> 7) & 7) << 4);
}

__device__ __forceinline__ unsigned short f2bf(float v) {
    __hip_bfloat16 h = __float2bfloat16(v);
    return *reinterpret_cast<unsigned short*>(&h);
}

__device__ __forceinline__ float bf2f(unsigned short u) {
    unsigned int x = ((unsigned int)u) << 16;
    return *reinterpret_cast<float*>(&x);
}

// async global->LDS, 16B per lane; zero VGPR cost.
// CONTRACT (m104/m108): LDS dest = readfirstlane(base) + lane*16. Only call with
// full-wave or lane-0-anchored-prefix exec and per-lane-linear lds addresses.
// The GLOBAL source address is per-lane (m173) — OOB lanes read a zero page.
__device__ __forceinline__ void gl16(const void* g, void* l) {
    __builtin_amdgcn_global_load_lds(
        (const __attribute__((address_space(1))) unsigned int*)g,
        (__attribute__((address_space(3))) unsigned int*)l, 16, 0, 0);
}

// ---------------- fused prep: weights + gmax + transpose in ONE launch ----------------
// blocks [0,72):    weight prep  f32 OIHW -> bf16 [kk][o][c] PRE-SWIZZLED (+ zero page)
// blocks [72,584):  gmax 3x3 maxpool of gate -> gmax image (scratch in `out`)
// blocks [584,2632): transpose x NCHW f32 -> xbf NHWC bf16 (4 tiles per block)
__global__ __launch_bounds__(1024)
void prep_all(const float* __restrict__ w1, const float* __restrict__ w2,
              const float* __restrict__ x, const float* __restrict__ gate,
              unsigned short* __restrict__ w1p, unsigned short* __restrict__ w2p,
              unsigned short* __restrict__ xbf, float* __restrict__ gmax,
              char* __restrict__ zpage) {
    __shared__ unsigned short tile[4][64 * 66];   // 33792 B (transpose section only)
    const int bx = blockIdx.x, t = threadIdx.x;

    if (bx < 72) {                                 // ---- weight prep ----
        if (bx == 0 && t == 0)
            *reinterpret_cast<uint4*>(zpage) = make_uint4(0u, 0u, 0u, 0u);
        int tid = bx * 1024 + t;
        if (tid < 2 * WELEM) {
            const float* src = (tid < WELEM) ? w1 : w2;
            unsigned short* dst = (tid < WELEM) ? w1p : w2p;
            int e = (tid < WELEM) ? tid : tid - WELEM;
            int c  = e & 63;
            int o  = (e >> 6) & 63;
            int kk = e >> 12;                      // 0..8
            int cs = c ^ ((o & 7) << 3);           // pre-swizzle
            dst[kk * 4096 + o * 64 + cs] = f2bf(src[o * 576 + c * 9 + kk]);
        }
        return;
    }
    if (bx < 584) {                                // ---- gmax ----
        int p = (bx - 72) * 1024 + t;              // 524288 px
        int b = p >> 16, rem = p & 65535, y = rem >> 8, xx0 = rem & 255;
        const float* gb = gate + (size_t)b * 65536;
        float m = 0.f;
        #pragma unroll
        for (int dy = -1; dy <= 1; ++dy)
            #pragma unroll
            for (int dx = -1; dx <= 1; ++dx) {
                int yy = y + dy, xx = xx0 + dx;
                if ((unsigned)yy < HH && (unsigned)xx < WW)
                    m = fmaxf(m, gb[yy * 256 + xx]);
            }
        gmax[p] = m;
        return;
    }
    // ---- transpose: 2048 blocks, 4 sub-tiles each; NON-TEMPORAL x loads ----
    // x is read exactly once in the whole pipeline: keep it out of L2/L3 so
    // xbf + h (reused by conv1/conv2) stay resident.
    const int sub = t >> 8, tt = t & 255;
    const int obx = (bx - 584) * 4 + sub;          // 0..8191
    const int xt = obx & 3, y = (obx >> 2) & 255, b = obx >> 10;
    const int x0 = xt * 64;
    const float* xb = x + (size_t)b * (64 * 65536) + y * 256 + x0;
    unsigned short* tl = tile[sub];
    #pragma unroll
    for (int it = 0; it < 4; ++it) {
        int idx = it * 256 + tt;
        int c = idx >> 4, xi = (idx & 15) * 4;
        f32x4 v = __builtin_nontemporal_load(
            reinterpret_cast<const f32x4*>(xb + (size_t)c * 65536 + xi));
        ushort4 o;
        o.x = f2bf(v[0]); o.y = f2bf(v[1]); o.z = f2bf(v[2]); o.w = f2bf(v[3]);
        *reinterpret_cast<ushort4*>(&tl[c * 66 + xi]) = o;
    }
    __syncthreads();                               // all 4 sub-tiles in same phase
    unsigned short* ob = xbf + ((size_t)(b * 65536 + y * 256 + x0)) * 64;
    #pragma unroll
    for (int it = 0; it < 2; ++it) {
        int idx = it * 256 + tt;
        int pix = idx >> 3, cg = idx & 7;
        unsigned short tmp[8];
        #pragma unroll
        for (int j = 0; j < 8; ++j) tmp[j] = tl[(cg * 8 + j) * 66 + pix];
        *reinterpret_cast<uint4*>(ob + (size_t)pix * 64 + cg * 8) = *reinterpret_cast<uint4*>(tmp);
    }
}

// ---------------- conv1 (r14 champion + zero-page OOB staging): xbf -> h ----------------
__global__ __launch_bounds__(1024, 1)
void conv1_kernel(const unsigned short* __restrict__ xbf, const float* __restrict__ gmaxg,
                  const unsigned short* __restrict__ wp,
                  const float* __restrict__ scale1, const float* __restrict__ bias1,
                  unsigned short* __restrict__ h, const char* __restrict__ zpage) {
    __shared__ __align__(16) unsigned short patch[NPIX * 64];  // 78336 B
    __shared__ __align__(16) unsigned short wlds[WELEM];       // 73728 B

    const int tid = threadIdx.x;
    const int bx  = blockIdx.x;                // 1024 = 8 tx * 16 ty * 8 b
    const int txi = bx & 7, tyi = (bx >> 3) & 15, b = bx >> 7;
    const int x0 = txi * TW, y0 = tyi * TH;

    char* pb = (char*)patch;
    char* wb = (char*)wlds;

    #pragma unroll
    for (int i = 0; i < 5; ++i) {
        int s = tid + i * 1024;
        if (s < WELEM / 8)
            gl16((const char*)wp + s * 16, wb + s * 16);
    }
    // patch staging: single branchless pass; OOB lanes source the zero page
    const unsigned short* hbase = xbf + (size_t)b * (65536 * 64);
    #pragma unroll
    for (int i = 0; i < 5; ++i) {
        int s = tid + i * 1024;
        if (s < NPIX * 8) {                    // prefix-safe guard only
            int p = s >> 3, j = s & 7;
            int row = p / PW, px = p - row * PW;
            int y = y0 - 1 + row, xg = x0 - 1 + px;
            bool valid = (unsigned)y < HH && (unsigned)xg < WW;
            int cc = j ^ (p & 7);
            const void* src = valid
                ? (const void*)(hbase + ((size_t)(y * 256 + xg) * 64 + cc * 8))
                : (const void*)zpage;
            gl16(src, pb + s * 16);
        }
    }
    __syncthreads();                           // drains vmcnt: all gl16 writes landed

    const int w = tid >> 6, l = tid & 63;
    const int l15 = l & 15, lq = l >> 4;

    float4v acc[2][4];
    #pragma unroll
    for (int m = 0; m < 2; ++m)
        #pragma unroll
        for (int n = 0; n < 4; ++n)
            acc[m][n] = (float4v){0.f, 0.f, 0.f, 0.f};

    #pragma unroll
    for (int kk = 0; kk < 9; ++kk) {
        const int ky = kk / 3, kx = kk - ky * 3;
        #pragma unroll
        for (int kc = 0; kc < 2; ++kc) {
            const int kbyte = kc * 64 + lq * 16;
            short8 a0 = *reinterpret_cast<const short8*>(pb + swz(((w + ky) * PW + l15 + kx) * 128 + kbyte));
            short8 a1 = *reinterpret_cast<const short8*>(pb + swz(((w + ky) * PW + 16 + l15 + kx) * 128 + kbyte));
            #pragma unroll
            for (int nt = 0; nt < 4; ++nt) {
                short8 bf = *reinterpret_cast<const short8*>(wb + swz((kk * 64 + nt * 16 + l15) * 128 + kbyte));
                acc[0][nt] = __builtin_amdgcn_mfma_f32_16x16x32_bf16(a0, bf, acc[0][nt], 0, 0, 0);
                acc[1][nt] = __builtin_amdgcn_mfma_f32_16x16x32_bf16(a1, bf, acc[1][nt], 0, 0, 0);
            }
        }
    }

    float s1v[4], b1v[4];
    #pragma unroll
    for (int nt = 0; nt < 4; ++nt) {
        s1v[nt] = scale1[nt * 16 + l15];
        b1v[nt] = bias1[nt * 16 + l15];
    }
    const int y = y0 + w;
    const float* gm = gmaxg + (size_t)b * 65536 + y * 256;
    unsigned short* hb = h + ((size_t)b * 65536 + (size_t)y * 256) * 64;
    #pragma unroll
    for (int m = 0; m < 2; ++m)
        #pragma unroll
        for (int r = 0; r < 4; ++r) {
            int px = m * 16 + lq * 4 + r;
            float g = gm[x0 + px];
            #pragma unroll
            for (int nt = 0; nt < 4; ++nt) {
                float v = acc[m][nt][r] * s1v[nt] + b1v[nt];
                v = fmaxf(v, 0.f) * g;
                hb[(size_t)(x0 + px) * 64 + nt * 16 + l15] = f2bf(v);
            }
        }
}

// ---------------- conv1 fallback (ws too small): round-8 version unchanged ----------------
__global__ __launch_bounds__(1024, 1)
void conv1_fallback(const float* __restrict__ x, const float* __restrict__ gate,
                    const unsigned short* __restrict__ wp,
                    const float* __restrict__ scale1, const float* __restrict__ bias1,
                    unsigned short* __restrict__ h) {
    __shared__ __align__(16) unsigned short patch[NPIX * 64];
    __shared__ __align__(16) unsigned short wlds[WELEM];
    __shared__ float gpatch[NPIX];
    __shared__ float gmax[TH * TW];

    const int tid = threadIdx.x;
    const int bx  = blockIdx.x;
    const int txi = bx & 7, tyi = (bx >> 3) & 15, b = bx >> 7;
    const int x0 = txi * TW, y0 = tyi * TH;

    char* pb = (char*)patch;
    char* wb = (char*)wlds;

    const float* xb = x + (size_t)b * (64 * 65536);
    for (int e = tid; e < NPIX * 64; e += 1024) {
        int c  = e / NPIX;
        int rp = e - c * NPIX;
        int row = rp / PW;
        int px  = rp - row * PW;
        int y = y0 - 1 + row, xg = x0 - 1 + px;
        float v = 0.f;
        if ((unsigned)y < HH && (unsigned)xg < WW)
            v = xb[(size_t)c * 65536 + y * 256 + xg];
        *reinterpret_cast<unsigned short*>(pb + swz(rp * 128 + c * 2)) = f2bf(v);
    }
    const float* gb = gate + (size_t)b * 65536;
    for (int e = tid; e < NPIX; e += 1024) {
        int row = e / PW, px = e - row * PW;
        int y = y0 - 1 + row, xg = x0 - 1 + px;
        gpatch[e] = ((unsigned)y < HH && (unsigned)xg < WW) ? gb[y * 256 + xg] : 0.f;
    }
    for (int s = tid; s < WELEM / 8; s += 1024) {
        *reinterpret_cast<uint4*>(wb + s * 16) =
            *reinterpret_cast<const uint4*>((const char*)wp + s * 16);
    }
    __syncthreads();

    if (tid < TH * TW) {
        int r = tid >> 5, px = tid & 31;
        float m = 0.f;
        #pragma unroll
        for (int dy = 0; dy < 3; ++dy)
            #pragma unroll
            for (int dx = 0; dx < 3; ++dx)
                m = fmaxf(m, gpatch[(r + dy) * PW + px + dx]);
        gmax[tid] = m;
    }
    __syncthreads();

    const int w = tid >> 6, l = tid & 63;
    const int l15 = l & 15, lq = l >> 4;

    float4v acc[2][4];
    #pragma unroll
    for (int m = 0; m < 2; ++m)
        #pragma unroll
        for (int n = 0; n < 4; ++n)
            acc[m][n] = (float4v){0.f, 0.f, 0.f, 0.f};

    #pragma unroll
    for (int kk = 0; kk < 9; ++kk) {
        const int ky = kk / 3, kx = kk - ky * 3;
        #pragma unroll
        for (int kc = 0; kc < 2; ++kc) {
            const int kbyte = kc * 64 + lq * 16;
            short8 a0 = *reinterpret_cast<const short8*>(pb + swz(((w + ky) * PW + l15 + kx) * 128 + kbyte));
            short8 a1 = *reinterpret_cast<const short8*>(pb + swz(((w + ky) * PW + 16 + l15 + kx) * 128 + kbyte));
            #pragma unroll
            for (int nt = 0; nt < 4; ++nt) {
                short8 bf = *reinterpret_cast<const short8*>(wb + swz((kk * 64 + nt * 16 + l15) * 128 + kbyte));
                acc[0][nt] = __builtin_amdgcn_mfma_f32_16x16x32_bf16(a0, bf, acc[0][nt], 0, 0, 0);
                acc[1][nt] = __builtin_amdgcn_mfma_f32_16x16x32_bf16(a1, bf, acc[1][nt], 0, 0, 0);
            }
        }
    }

    float s1v[4], b1v[4];
    #pragma unroll
    for (int nt = 0; nt < 4; ++nt) {
        s1v[nt] = scale1[nt * 16 + l15];
        b1v[nt] = bias1[nt * 16 + l15];
    }
    const int y = y0 + w;
    unsigned short* hb = h + ((size_t)b * 65536 + (size_t)y * 256) * 64;
    #pragma unroll
    for (int m = 0; m < 2; ++m)
        #pragma unroll
        for (int r = 0; r < 4; ++r) {
            int px = m * 16 + lq * 4 + r;
            float g = gmax[w * 32 + px];
            #pragma unroll
            for (int nt = 0; nt < 4; ++nt) {
                float v = acc[m][nt][r] * s1v[nt] + b1v[nt];
                v = fmaxf(v, 0.f) * g;
                hb[(size_t)(x0 + px) * 64 + nt * 16 + l15] = f2bf(v);
            }
        }
}

// ---------------- conv2 (r14 champion + zero-page OOB staging): h -> out + residual ----------------
__global__ __launch_bounds__(1024, 1)
void conv2_kernel(const unsigned short* __restrict__ h, const float* __restrict__ x,
                  const unsigned short* __restrict__ xr16,
                  const float* __restrict__ gate, const unsigned short* __restrict__ wp,
                  const float* __restrict__ scale2, const float* __restrict__ bias2,
                  float* __restrict__ out, const char* __restrict__ zpage) {
    __shared__ __align__(16) unsigned short patch[NPIX * 64];
    __shared__ __align__(16) unsigned short wlds[WELEM];

    const int tid = threadIdx.x;
    const int bx  = blockIdx.x;
    const int txi = bx & 7, tyi = (bx >> 3) & 15, b = bx >> 7;
    const int x0 = txi * TW, y0 = tyi * TH;

    char* pb = (char*)patch;
    char* wb = (char*)wlds;

    #pragma unroll
    for (int i = 0; i < 5; ++i) {
        int s = tid + i * 1024;
        if (s < WELEM / 8)
            gl16((const char*)wp + s * 16, wb + s * 16);
    }
    const unsigned short* hbase = h + (size_t)b * (65536 * 64);
    #pragma unroll
    for (int i = 0; i < 5; ++i) {
        int s = tid + i * 1024;
        if (s < NPIX * 8) {
            int p = s >> 3, j = s & 7;
            int row = p / PW, px = p - row * PW;
            int y = y0 - 1 + row, xg = x0 - 1 + px;
            bool valid = (unsigned)y < HH && (unsigned)xg < WW;
            int cc = j ^ (p & 7);
            const void* src = valid
                ? (const void*)(hbase + ((size_t)(y * 256 + xg) * 64 + cc * 8))
                : (const void*)zpage;
            gl16(src, pb + s * 16);
        }
    }
    __syncthreads();                           // drains vmcnt: all gl16 writes landed

    const int w = tid >> 6, l = tid & 63;      // 16 waves, wave = output row
    const int l15 = l & 15, lq = l >> 4;

    float4v acc[4][2];                         // [oc-frag][px-half]
    #pragma unroll
    for (int m = 0; m < 4; ++m)
        #pragma unroll
        for (int n = 0; n < 2; ++n)
            acc[m][n] = (float4v){0.f, 0.f, 0.f, 0.f};

    #pragma unroll
    for (int kk = 0; kk < 9; ++kk) {
        const int ky = kk / 3, kx = kk - ky * 3;
        #pragma unroll
        for (int kc = 0; kc < 2; ++kc) {
            const int kbyte = kc * 64 + lq * 16;
            short8 bp0 = *reinterpret_cast<const short8*>(pb + swz(((w + ky) * PW + l15 + kx) * 128 + kbyte));
            short8 bp1 = *reinterpret_cast<const short8*>(pb + swz(((w + ky) * PW + 16 + l15 + kx) * 128 + kbyte));
            #pragma unroll
            for (int mt = 0; mt < 4; ++mt) {
                short8 aw = *reinterpret_cast<const short8*>(wb + swz((kk * 64 + mt * 16 + l15) * 128 + kbyte));
                acc[mt][0] = __builtin_amdgcn_mfma_f32_16x16x32_bf16(aw, bp0, acc[mt][0], 0, 0, 0);
                acc[mt][1] = __builtin_amdgcn_mfma_f32_16x16x32_bf16(aw, bp1, acc[mt][1], 0, 0, 0);
            }
        }
    }

    // epilogue: BN2 + *gate + residual + ReLU, NON-TEMPORAL NCHW f32 stores
    // (out is write-only, never re-read: keep its 134 MB out of L2/L3)
    const int y = y0 + w;
    const float* gr = gate + (size_t)b * 65536 + y * 256 + x0;
    float g0 = gr[l15], g1 = gr[16 + l15];
    #pragma unroll
    for (int mt = 0; mt < 4; ++mt) {
        float sc4[4], bi4[4];
        #pragma unroll
        for (int r = 0; r < 4; ++r) {
            int oc = mt * 16 + lq * 4 + r;
            sc4[r] = scale2[oc];
            bi4[r] = bias2[oc];
        }
        #pragma unroll
        for (int nt = 0; nt < 2; ++nt) {
            int px = nt * 16 + l15;
            float g = nt ? g1 : g0;
            float xv[4];
            if (xr16) {
                // residual from bf16 NHWC copy: 4 consecutive oc = one ushort4
                size_t pix = (size_t)b * 65536 + (size_t)y * 256 + x0 + px;
                ushort4 u = *reinterpret_cast<const ushort4*>(xr16 + pix * 64 + mt * 16 + lq * 4);
                xv[0] = bf2f(u.x); xv[1] = bf2f(u.y); xv[2] = bf2f(u.z); xv[3] = bf2f(u.w);
            } else {
                #pragma unroll
                for (int r = 0; r < 4; ++r) {
                    int oc = mt * 16 + lq * 4 + r;
                    xv[r] = x[((size_t)(b * 64 + oc) * 256 + y) * 256 + x0 + px];
                }
            }
            #pragma unroll
            for (int r = 0; r < 4; ++r) {
                int oc = mt * 16 + lq * 4 + r;
                size_t base = ((size_t)(b * 64 + oc) * 256 + y) * 256 + x0;
                float v = acc[mt][nt][r] * sc4[r] + bi4[r];
                v = v * g + xv[r];
                __builtin_nontemporal_store(fmaxf(v, 0.f), &out[base + px]);
            }
        }
    }
}

extern "C" void kernel_launch(void* const* d_in, const int* in_sizes, int n_in,
                              void* d_out, int out_size, void* d_ws, size_t ws_size,
                              hipStream_t stream) {
    const float* x      = (const float*)d_in[0];
    const float* gate   = (const float*)d_in[1];
    const float* w1     = (const float*)d_in[2];
    const float* scale1 = (const float*)d_in[3];
    const float* bias1  = (const float*)d_in[4];
    const float* w2     = (const float*)d_in[5];
    const float* scale2 = (const float*)d_in[6];
    const float* bias2  = (const float*)d_in[7];
    float* out = (float*)d_out;

    char* ws = (char*)d_ws;
    const size_t HBYTES = 67108864;            // 64 MiB NHWC bf16 h
    const size_t NEED_BIG = 2 * HBYTES + 2 * 73728 + 16;

    // gmax (3x3 maxpool of gate) lives in `out` as scratch: consumed only by conv1,
    // then conv2 fully overwrites out (stream-ordered). Proven rounds 5-14.
    float* gmaxbuf = out;

    if (ws_size >= NEED_BIG) {
        unsigned short* hbuf = (unsigned short*)ws;
        unsigned short* xbf  = (unsigned short*)(ws + HBYTES);
        unsigned short* w1p  = (unsigned short*)(ws + 2 * HBYTES);
        unsigned short* w2p  = (unsigned short*)(ws + 2 * HBYTES + 73728);
        char* zpage          = ws + 2 * HBYTES + 2 * 73728;
        prep_all<<<2632, 1024, 0, stream>>>(w1, w2, x, gate, w1p, w2p, xbf, gmaxbuf, zpage);
        conv1_kernel<<<1024, 1024, 0, stream>>>(xbf, gmaxbuf, w1p, scale1, bias1, hbuf, zpage);
        conv2_kernel<<<1024, 1024, 0, stream>>>(hbuf, x, xbf, gate, w2p, scale2, bias2, out, zpage);
    } else {
        unsigned short* hbuf = (unsigned short*)ws;
        unsigned short* w1p  = (unsigned short*)(ws + HBYTES);
        unsigned short* w2p  = (unsigned short*)(ws + HBYTES + 73728);
        char* zpage          = ws + HBYTES + 2 * 73728;
        // fallback: only the 72 weight-prep blocks (no gmax/transpose sections launched)
        prep_all<<<72, 1024, 0, stream>>>(w1, w2, x, gate, w1p, w2p, nullptr, nullptr, zpage);
        conv1_fallback<<<1024, 1024, 0, stream>>>(x, gate, w1p, scale1, bias1, hbuf);
        conv2_kernel<<<1024, 1024, 0, stream>>>(hbuf, x, nullptr, gate, w2p, scale2, bias2, out, zpage);
    }
}